// Round 8
// baseline (2253.726 us; speedup 1.0000x reference)
//
#include <hip/hip_runtime.h>
#include <math.h>

// Bidirectional 10-layer tanh RNN, T=512 B=64 H=100, + sigmoid head.
// Layers strictly sequential (bidir dependency). Per layer:
//   1) ingemm_kernel: z[dir][m][h] = In[m][:] . W[dir*100+h][:] + bias
//   2) scan_kernel:   128 blocks = 2 dirs x 64 batch independent chains
// Final: outproj_kernel (wave-per-row dot200 + sigmoid).
//
// R8: ingemm double-buffered (T3 2-phase + T14 issue-early/write-late).
// R7 showed the inner-loop FMA:DS ratio is irrelevant (64->128 M-tile was
// exactly neutral): ingemm is staging-latency bound -- each chunk's
// global->LDS->barrier path put an L2/L3 round trip on the critical path.
// Now: issue chunk c+1 loads into regs BEFORE compute(c), ds_write AFTER
// (vmcnt wait lands post-compute), one barrier per chunk. LDS 25.6 KB.
// scan: R6 version, banked at its turnaround floor (173.6us, 0 conflicts).

#define T_LEN 512
#define BATCH 64
#define HID   100
#define M_TOT (T_LEN * BATCH)   // 32768

// ---------------- input GEMM (128x64 tile, double-buffered staging) ----------------
// Grid: (M_TOT/128, 4). Block 256: tx = tid&15 (4 cols), ty = tid>>4
// (8 rows: ty*4..+3 and 64+ty*4..+3).
__global__ __launch_bounds__(256) void ingemm_kernel(
    const float* __restrict__ In, const float* __restrict__ W,
    const float* __restrict__ bih, const float* __restrict__ bhh,
    float* __restrict__ z, int K)
{
    __shared__ float As[2][16][132];   // [buf][k][m], 128 rows + pad
    __shared__ float Bs[2][16][68];    // [buf][k][n], 64 cols + pad
    const int tid = threadIdx.x;
    const int m0 = blockIdx.x * 128;
    const int n0 = blockIdx.y * 64;
    const int tx = tid & 15, ty = tid >> 4;
    const int lm = tid >> 2;          // 0..63
    const int lk = (tid & 3) << 2;    // 0,4,8,12
    const int NC = (K + 15) >> 4;     // 13 for K=200, 7 for K=100

    const float* Arow0 = In + (size_t)(m0 + lm) * K + lk;
    const float* Arow1 = In + (size_t)(m0 + 64 + lm) * K + lk;
    const int nrow = n0 + lm;
    const bool bok = (nrow < 200);
    const float* Brow = W + (size_t)(bok ? nrow : 0) * K + lk;

    float acc[8][4];
    #pragma unroll
    for (int i = 0; i < 8; ++i)
        #pragma unroll
        for (int j = 0; j < 4; ++j) acc[i][j] = 0.f;

// load chunk (k0 = 16*c) into regs; K%4==0 so a 4-chunk is fully in or out
#define GLOAD(A0, A1, BV, k0)                                           \
  do {                                                                  \
    A0 = make_float4(0.f,0.f,0.f,0.f);                                  \
    A1 = make_float4(0.f,0.f,0.f,0.f);                                  \
    BV = make_float4(0.f,0.f,0.f,0.f);                                  \
    if ((k0) + lk < K) {                                                \
      A0 = *(const float4*)(Arow0 + (k0));                              \
      A1 = *(const float4*)(Arow1 + (k0));                              \
      if (bok) BV = *(const float4*)(Brow + (k0));                      \
    }                                                                   \
  } while (0)

#define LWRITE(BUF, A0, A1, BV)                                         \
  do {                                                                  \
    As[BUF][lk+0][lm] = A0.x; As[BUF][lk+1][lm] = A0.y;                 \
    As[BUF][lk+2][lm] = A0.z; As[BUF][lk+3][lm] = A0.w;                 \
    As[BUF][lk+0][64+lm] = A1.x; As[BUF][lk+1][64+lm] = A1.y;           \
    As[BUF][lk+2][64+lm] = A1.z; As[BUF][lk+3][64+lm] = A1.w;           \
    Bs[BUF][lk+0][lm] = BV.x; Bs[BUF][lk+1][lm] = BV.y;                 \
    Bs[BUF][lk+2][lm] = BV.z; Bs[BUF][lk+3][lm] = BV.w;                 \
  } while (0)

    // prologue: chunk 0 staged into buf 0
    float4 a0v, a1v, bv;
    GLOAD(a0v, a1v, bv, 0);
    LWRITE(0, a0v, a1v, bv);
    __syncthreads();

    int cur = 0;
    for (int c = 0; c < NC; ++c) {
        // issue next chunk's global loads early (latency hides under compute)
        float4 na0, na1, nb;
        const bool more = (c + 1 < NC);
        if (more) GLOAD(na0, na1, nb, 16 * (c + 1));
        __builtin_amdgcn_sched_barrier(0);   // keep loads issued above compute

        const float (*Ac)[132] = As[cur];
        const float (*Bc)[68]  = Bs[cur];
        #pragma unroll
        for (int kk = 0; kk < 16; ++kk) {
            float4 alo = *(const float4*)&Ac[kk][ty << 2];
            float4 ahi = *(const float4*)&Ac[kk][64 + (ty << 2)];
            float4 b4  = *(const float4*)&Bc[kk][tx << 2];
            float a[8] = {alo.x, alo.y, alo.z, alo.w,
                          ahi.x, ahi.y, ahi.z, ahi.w};
            float b[4] = {b4.x, b4.y, b4.z, b4.w};
            #pragma unroll
            for (int i = 0; i < 8; ++i)
                #pragma unroll
                for (int j = 0; j < 4; ++j)
                    acc[i][j] += a[i] * b[j];
        }

        // write-late: vmcnt wait lands here, AFTER compute
        if (more) LWRITE(cur ^ 1, na0, na1, nb);
        __syncthreads();
        cur ^= 1;
    }
#undef GLOAD
#undef LWRITE

    #pragma unroll
    for (int i = 0; i < 8; ++i) {
        const int m = m0 + ((i < 4) ? ((ty << 2) + i) : (64 + (ty << 2) + (i - 4)));
        #pragma unroll
        for (int j = 0; j < 4; ++j) {
            const int n = n0 + (tx << 2) + j;
            if (n < 200) {
                const int dir = (n >= 100) ? 1 : 0;
                const int h = n - dir * 100;
                z[(size_t)dir * M_TOT * HID + (size_t)m * HID + h] =
                    acc[i][j] + bih[n] + bhh[n];
            }
        }
    }
}

// DPP helpers — guaranteed VALU lane exchange (no LDS).
// quad_perm ctrl = p0|p1<<2|p2<<4|p3<<6: xor1 {1,0,3,2}=0xB1, xor2 {2,3,0,1}=0x4E.
// row_half_mirror (lane^7 within groups of 8) = 0x141.
__device__ __forceinline__ float dpp_qxor1(float x) {
    int i = __float_as_int(x);
    i = __builtin_amdgcn_update_dpp(0, i, 0xB1, 0xF, 0xF, false);
    return __int_as_float(i);
}
__device__ __forceinline__ float dpp_qxor2(float x) {
    int i = __float_as_int(x);
    i = __builtin_amdgcn_update_dpp(0, i, 0x4E, 0xF, 0xF, false);
    return __int_as_float(i);
}
__device__ __forceinline__ float dpp_hmir(float x) {  // lane ^ 7
    int i = __float_as_int(x);
    i = __builtin_amdgcn_update_dpp(0, i, 0x141, 0xF, 0xF, false);
    return __int_as_float(i);
}

// ---------------- recurrent scan (R6, banked at turnaround floor) ----------------
// One block (256 threads, 4 waves) per (dir, batch) chain.
// Lane: q=lane&3, b2=(lane>>2)&1 -> ks = q|(b2<<2) in [0,8);
// slot = (lane>>3) + 8*wave in [0,32), active < 25; rows = 4*slot + r.
// Slice ks reads h[12ks .. 12ks+16); owns k in [12ks+4,12ks+16) (ks>0) or
// [0,16) (ks==0) -> exact partition of [0,100). Reduce over 8 slices:
// hop lane^7 (row_half_mirror, rows preserved since all 4 accs live), then
// quad xor1/xor2 transpose -> lane ends with row q total; writers b2==0.
__global__ __launch_bounds__(256) void scan_kernel(
    const float* __restrict__ z,    // [2][M][HID]
    const float* __restrict__ Whh,  // [2][HID][HID] for this layer
    float* __restrict__ out)        // [M][200]
{
    const int dir = blockIdx.x >> 6;
    const int b   = blockIdx.x & 63;
    const int tid = threadIdx.x;        // 0..255
    const int w   = tid >> 6;           // wave 0..3
    const int lane= tid & 63;
    const int q   = lane & 3;
    const int b2  = (lane >> 2) & 1;
    const int ks  = q | (b2 << 2);      // k-slice 0..7
    const int slot= (lane >> 3) + 8 * w;    // 0..31
    const bool active = (slot < 25);
    const int slotc = active ? slot : 24;
    const int jout = 4 * slotc + q;     // row this lane finalizes (0..99)
    const bool writer = active && (b2 == 0);
    const int kb = 12 * ks;             // slice base (floats); 12*7+16 = 100

    __shared__ float h_lds[2][112];
    for (int i = tid; i < 224; i += 256) (&h_lds[0][0])[i] = 0.f;

    // per-lane weights: w4[r][kk] = Whh[dir][4*slot+r][kb+kk];
    // zero kk<4 for ks>0 (owned-k partition; no double counting).
    float w4[4][16];
    #pragma unroll
    for (int r = 0; r < 4; ++r) {
        const float* wr = Whh + ((size_t)dir * HID + 4 * slotc + r) * HID + kb;
        #pragma unroll
        for (int i = 0; i < 4; ++i) {
            float4 v = *(const float4*)(wr + 4 * i);
            w4[r][4*i+0] = v.x; w4[r][4*i+1] = v.y;
            w4[r][4*i+2] = v.z; w4[r][4*i+3] = v.w;
        }
        if (ks > 0) {
            w4[r][0] = 0.f; w4[r][1] = 0.f; w4[r][2] = 0.f; w4[r][3] = 0.f;
        }
    }
    __syncthreads();   // h_lds zero-init visible

    const ptrdiff_t zstride = BATCH * HID;
    const ptrdiff_t ostride = BATCH * 200;
    const int t0 = dir ? (T_LEN - 1) : 0;
    const ptrdiff_t zstep = dir ? -zstride : zstride;
    const ptrdiff_t ostep = dir ? -ostride : ostride;
    const ptrdiff_t zstep2 = 2 * zstep, zstep3 = 3 * zstep, zstep4 = 4 * zstep;

    const float* zp = z + (size_t)dir * M_TOT * HID + (size_t)b * HID + jout
                        + (ptrdiff_t)t0 * zstride;
    float*       op = out + (size_t)b * 200 + dir * HID + jout
                        + (ptrdiff_t)t0 * ostride;

    // 4-deep z prefetch ring (statically indexed named regs)
    float zr0 = zp[0];
    float zr1 = zp[zstep];
    float zr2 = zp[zstep2];
    float zr3 = zp[zstep3];
    const float* zpf = zp + zstep4;

// One step: 4 b128 LDS reads (8 distinct slices cover all 32 banks once,
// broadcast x8), 64 FMAs vs register weights (4 rows x 16), 3-hop all-DPP
// reduce (lane^7 first while 4 accs live, then quad xor1/xor2 transpose),
// tanh, conflict-free ds_write_b32 from b2==0 lanes. Raw barrier: lgkm only.
#define RNN_STEP(ZREG, DO_PF, PFOFF, RD, WRB)                           \
  do {                                                                  \
    const float zin = ZREG;                                             \
    if (DO_PF) ZREG = *(zpf + (PFOFF));   /* fire-and-forget prefetch */\
    const float4* hp = (const float4*)((RD) + kb);                      \
    float a0 = 0.f, a1 = 0.f, a2 = 0.f, a3 = 0.f;                       \
    _Pragma("unroll")                                                   \
    for (int i = 0; i < 4; ++i) {                                       \
      float4 hv = hp[i];                                                \
      a0 += w4[0][4*i+0] * hv.x; a0 += w4[0][4*i+1] * hv.y;             \
      a0 += w4[0][4*i+2] * hv.z; a0 += w4[0][4*i+3] * hv.w;             \
      a1 += w4[1][4*i+0] * hv.x; a1 += w4[1][4*i+1] * hv.y;             \
      a1 += w4[1][4*i+2] * hv.z; a1 += w4[1][4*i+3] * hv.w;             \
      a2 += w4[2][4*i+0] * hv.x; a2 += w4[2][4*i+1] * hv.y;             \
      a2 += w4[2][4*i+2] * hv.z; a2 += w4[2][4*i+3] * hv.w;             \
      a3 += w4[3][4*i+0] * hv.x; a3 += w4[3][4*i+1] * hv.y;             \
      a3 += w4[3][4*i+2] * hv.z; a3 += w4[3][4*i+3] * hv.w;             \
    }                                                                   \
    /* hop lane^7: rows preserved (all 4 accs), slices s + s^7 */       \
    float t0_ = a0 + dpp_hmir(a0);                                      \
    float t1_ = a1 + dpp_hmir(a1);                                      \
    float t2_ = a2 + dpp_hmir(a2);                                      \
    float t3_ = a3 + dpp_hmir(a3);                                      \
    /* quad xor1: keep rows r&1==q&1 */                                 \
    float k01 = (q & 1) ? t1_ : t0_;                                    \
    float s01s = (q & 1) ? t0_ : t1_;                                   \
    float s01 = k01 + dpp_qxor1(s01s);                                  \
    float k23 = (q & 1) ? t3_ : t2_;                                    \
    float s23s = (q & 1) ? t2_ : t3_;                                   \
    float s23 = k23 + dpp_qxor1(s23s);                                  \
    /* quad xor2: keep rows r&2==q&2 -> row q total over 8 slices */    \
    float kf = (q & 2) ? s23 : s01;                                     \
    float sf = (q & 2) ? s01 : s23;                                     \
    float tot = kf + dpp_qxor2(sf);                                     \
    float xin = zin + tot;                                              \
    float ax = fabsf(xin);                                              \
    float e = __expf(2.f * ax);                                         \
    float r = 1.f - 2.f / (e + 1.f);                                    \
    float val = copysignf(r, xin);                                      \
    if (writer) {                                                       \
      (WRB)[jout] = val;                                                \
      *op = val;                                                        \
    }                                                                   \
    op += ostep;                                                        \
    asm volatile("s_waitcnt lgkmcnt(0)" ::: "memory");                  \
    __builtin_amdgcn_sched_barrier(0);                                  \
    __builtin_amdgcn_s_barrier();                                       \
    __builtin_amdgcn_sched_barrier(0);                                  \
  } while (0)

    float* const h0 = &h_lds[0][0];
    float* const h1 = &h_lds[1][0];

    // main: 127 groups of 4 steps, prefetching steps s+4..s+7
    for (int g = 0; g < (T_LEN / 4) - 1; ++g) {
        RNN_STEP(zr0, 1, 0,      h0, h1);
        RNN_STEP(zr1, 1, zstep,  h1, h0);
        RNN_STEP(zr2, 1, zstep2, h0, h1);
        RNN_STEP(zr3, 1, zstep3, h1, h0);
        zpf += zstep4;
    }
    // tail: last 4 steps, no prefetch
    RNN_STEP(zr0, 0, 0, h0, h1);
    RNN_STEP(zr1, 0, 0, h1, h0);
    RNN_STEP(zr2, 0, 0, h0, h1);
    RNN_STEP(zr3, 0, 0, h1, h0);

#undef RNN_STEP
}

// ---------------- output projection ----------------
__global__ __launch_bounds__(256) void outproj_kernel(
    const float* __restrict__ h, const float* __restrict__ Wout,
    const float* __restrict__ bout, float* __restrict__ y)
{
    const int gid = blockIdx.x * 256 + threadIdx.x;
    const int wid = gid >> 6;
    const int lane = threadIdx.x & 63;
    if (wid >= M_TOT) return;
    const float* row = h + (size_t)wid * 200;
    float acc = 0.f;
    for (int k = lane; k < 200; k += 64) acc += row[k] * Wout[k];
    #pragma unroll
    for (int off = 32; off > 0; off >>= 1) acc += __shfl_xor(acc, off);
    if (lane == 0) y[wid] = 1.f / (1.f + __expf(-(acc + bout[0])));
}

extern "C" void kernel_launch(void* const* d_in, const int* in_sizes, int n_in,
                              void* d_out, int out_size, void* d_ws, size_t ws_size,
                              hipStream_t stream)
{
    const float* x     = (const float*)d_in[0];
    const float* W_ih0 = (const float*)d_in[1];
    const float* W_ih  = (const float*)d_in[2];
    const float* W_hh  = (const float*)d_in[3];
    const float* b_ih  = (const float*)d_in[4];
    const float* b_hh  = (const float*)d_in[5];
    const float* W_out = (const float*)d_in[6];
    const float* b_out = (const float*)d_in[7];
    float* y = (float*)d_out;

    float* z    = (float*)d_ws;                          // 2*M*100 floats
    float* buf0 = z + (size_t)2 * M_TOT * HID;           // M*200
    float* buf1 = buf0 + (size_t)M_TOT * 200;            // M*200

    for (int l = 0; l < 10; ++l) {
        const float* In = (l == 0) ? x : ((l & 1) ? buf0 : buf1);
        float* Out      = (l & 1) ? buf1 : buf0;
        const int K     = (l == 0) ? 100 : 200;
        const float* W  = (l == 0) ? W_ih0 : (W_ih + (size_t)(l - 1) * 2 * 100 * 200);
        ingemm_kernel<<<dim3(M_TOT / 128, 4), 256, 0, stream>>>(
            In, W, b_ih + l * 200, b_hh + l * 200, z, K);
        scan_kernel<<<128, 256, 0, stream>>>(
            z, W_hh + (size_t)l * 2 * HID * HID, Out);
    }
    outproj_kernel<<<M_TOT / 4, 256, 0, stream>>>(buf1, W_out, b_out, y);
}

// Round 9
// 2110.198 us; speedup vs baseline: 1.0680x; 1.0680x over previous
//
#include <hip/hip_runtime.h>
#include <math.h>

// Bidirectional 10-layer tanh RNN, T=512 B=64 H=100, + sigmoid head.
// R9: ingemm for layers 1..9 moved to the MATRIX pipe via split-bf16
// (hi/lo) 3-term MFMA: x*w ~= hi*wh + hi*wl + lo*wh, fp32-grade precision
// at ~794 TF effective (5x vector fp32 peak). Scan writes h as bf16 hi/lo
// pairs directly ([M][224] zero-padded); W split per layer into [208][224]
// zero-padded bf16 (pads absorb K=200->224, N=200->208 edges). Layer 0
// (fp32 x, K=100) keeps the proven R7 fp32 ingemm. outproj reads hi+lo.
// scan: R6 core unchanged (banked at its 173.6us turnaround floor);
// fp32 out store replaced by two b16 stores (fire-and-forget, no drain).

#define T_LEN 512
#define BATCH 64
#define HID   100
#define M_TOT (T_LEN * BATCH)   // 32768
#define KPAD  224               // 7 chunks of 32
#define NPAD  208               // 13 tiles of 16

typedef unsigned short ushort_t;
typedef __attribute__((ext_vector_type(8))) __bf16 bf16x8;
typedef __attribute__((ext_vector_type(4))) float f32x4;

// ---------------- fp32 input GEMM, layer 0 only (R7 structure, proven) ----------------
// Grid: (M_TOT/128, 4). Block 256: tx = tid&15 (4 cols), ty = tid>>4 (8 rows).
__global__ __launch_bounds__(256) void ingemm_kernel(
    const float* __restrict__ In, const float* __restrict__ W,
    const float* __restrict__ bih, const float* __restrict__ bhh,
    float* __restrict__ z, int K)
{
    __shared__ float As[16][132];
    __shared__ float Bs[16][68];
    const int tid = threadIdx.x;
    const int m0 = blockIdx.x * 128;
    const int n0 = blockIdx.y * 64;
    const int tx = tid & 15, ty = tid >> 4;
    const int lm = tid >> 2;
    const int lk = (tid & 3) << 2;

    float acc[8][4];
    #pragma unroll
    for (int i = 0; i < 8; ++i)
        #pragma unroll
        for (int j = 0; j < 4; ++j) acc[i][j] = 0.f;

    for (int k0 = 0; k0 < K; k0 += 16) {
        #pragma unroll
        for (int rep = 0; rep < 2; ++rep) {
            float4 av = make_float4(0.f,0.f,0.f,0.f);
            const int row = lm + 64 * rep;
            if (k0 + lk < K)
                av = *(const float4*)(In + (size_t)(m0 + row) * K + k0 + lk);
            As[lk+0][row]=av.x; As[lk+1][row]=av.y;
            As[lk+2][row]=av.z; As[lk+3][row]=av.w;
        }
        {
            float4 bv = make_float4(0.f,0.f,0.f,0.f);
            const int nrow = n0 + lm;
            if (nrow < 200 && k0 + lk < K)
                bv = *(const float4*)(W + (size_t)nrow * K + k0 + lk);
            Bs[lk+0][lm]=bv.x; Bs[lk+1][lm]=bv.y;
            Bs[lk+2][lm]=bv.z; Bs[lk+3][lm]=bv.w;
        }
        __syncthreads();
        #pragma unroll
        for (int kk = 0; kk < 16; ++kk) {
            float4 alo = *(const float4*)&As[kk][ty << 2];
            float4 ahi = *(const float4*)&As[kk][64 + (ty << 2)];
            float4 b4  = *(const float4*)&Bs[kk][tx << 2];
            float a[8] = {alo.x, alo.y, alo.z, alo.w,
                          ahi.x, ahi.y, ahi.z, ahi.w};
            float b[4] = {b4.x, b4.y, b4.z, b4.w};
            #pragma unroll
            for (int i = 0; i < 8; ++i)
                #pragma unroll
                for (int j = 0; j < 4; ++j)
                    acc[i][j] += a[i] * b[j];
        }
        __syncthreads();
    }
    #pragma unroll
    for (int i = 0; i < 8; ++i) {
        const int m = m0 + ((i < 4) ? ((ty << 2) + i) : (64 + (ty << 2) + (i - 4)));
        #pragma unroll
        for (int j = 0; j < 4; ++j) {
            const int n = n0 + (tx << 2) + j;
            if (n < 200) {
                const int dir = (n >= 100) ? 1 : 0;
                const int h = n - dir * 100;
                z[(size_t)dir * M_TOT * HID + (size_t)m * HID + h] =
                    acc[i][j] + bih[n] + bhh[n];
            }
        }
    }
}

// ---------------- helpers: bf16 RNE split ----------------
__device__ __forceinline__ unsigned bf16_rne(float v) {
    unsigned u = __float_as_uint(v);
    return (u + 0x7FFFu + ((u >> 16) & 1u)) >> 16;
}

// zero the pad columns (200..223) of the 4 hi/lo ping-pong arrays
__global__ __launch_bounds__(256) void zeropad_kernel(
    ushort_t* a, ushort_t* b, ushort_t* c, ushort_t* d)
{
    int i = blockIdx.x * 256 + threadIdx.x;      // M*24
    if (i >= M_TOT * 24) return;
    size_t off = (size_t)(i / 24) * KPAD + 200 + (i % 24);
    a[off] = 0; b[off] = 0; c[off] = 0; d[off] = 0;
}

// split W (fp32 [200][200]) into zero-padded bf16 hi/lo [NPAD][KPAD]
__global__ __launch_bounds__(256) void wsplit_kernel(
    const float* __restrict__ W, ushort_t* __restrict__ whi,
    ushort_t* __restrict__ wlo)
{
    int i = blockIdx.x * 256 + threadIdx.x;      // NPAD*KPAD = 46592
    if (i >= NPAD * KPAD) return;
    int n = i / KPAD, k = i % KPAD;
    float v = (n < 200 && k < 200) ? W[n * 200 + k] : 0.f;
    unsigned hr = bf16_rne(v);
    float hv = __uint_as_float(hr << 16);
    unsigned lr = bf16_rne(v - hv);
    whi[i] = (ushort_t)hr;
    wlo[i] = (ushort_t)lr;
}

// ---------------- MFMA input GEMM, layers 1..9 ----------------
// z[m][n] = sum_k In[m][k] W[n][k], In = hi+lo bf16 [M][KPAD], W split
// [NPAD][KPAD]. One wave per 16-row m-tile; A hi/lo frags resident; loop 13
// n-tiles x 7 k-chunks x 3 MFMA (hh, hl, lh). Fragment layout: lane ->
// (row = lane&15, k = 8*(lane>>4)+b) for both A and B (contiguous 16B
// loads); D: col = lane&15, row = (lane>>4)*4 + reg (HW-verified mapping).
__global__ __launch_bounds__(256) void ingemm_mfma_kernel(
    const ushort_t* __restrict__ in_hi, const ushort_t* __restrict__ in_lo,
    const ushort_t* __restrict__ w_hi,  const ushort_t* __restrict__ w_lo,
    const float* __restrict__ bih, const float* __restrict__ bhh,
    float* __restrict__ z)
{
    const int wv   = threadIdx.x >> 6;
    const int lane = threadIdx.x & 63;
    const int mt   = blockIdx.x * 4 + wv;     // m-tile 0..2047
    const int m0   = mt * 16;
    const int r16  = lane & 15;               // A-row / B-col within tile
    const int kg   = lane >> 4;               // k-group 0..3
    const int kof  = kg * 8;

    // A fragments: 7 k-chunks x {hi, lo}
    bf16x8 ah[7], al[7];
    const ushort_t* arh = in_hi + (size_t)(m0 + r16) * KPAD + kof;
    const ushort_t* arl = in_lo + (size_t)(m0 + r16) * KPAD + kof;
    #pragma unroll
    for (int c = 0; c < 7; ++c) {
        ah[c] = *(const bf16x8*)(arh + 32 * c);
        al[c] = *(const bf16x8*)(arl + 32 * c);
    }

    for (int nt = 0; nt < 13; ++nt) {
        const int n0 = nt * 16;
        const ushort_t* brh = w_hi + (size_t)(n0 + r16) * KPAD + kof;
        const ushort_t* brl = w_lo + (size_t)(n0 + r16) * KPAD + kof;
        f32x4 acc = {0.f, 0.f, 0.f, 0.f};
        #pragma unroll
        for (int c = 0; c < 7; ++c) {
            bf16x8 bh = *(const bf16x8*)(brh + 32 * c);
            bf16x8 bl = *(const bf16x8*)(brl + 32 * c);
            acc = __builtin_amdgcn_mfma_f32_16x16x32_bf16(ah[c], bh, acc, 0, 0, 0);
            acc = __builtin_amdgcn_mfma_f32_16x16x32_bf16(ah[c], bl, acc, 0, 0, 0);
            acc = __builtin_amdgcn_mfma_f32_16x16x32_bf16(al[c], bh, acc, 0, 0, 0);
        }
        const int n = n0 + r16;               // D col
        if (n < 200) {
            const int dir = (n >= 100) ? 1 : 0;
            const int h = n - dir * 100;
            const float bias = bih[n] + bhh[n];
            #pragma unroll
            for (int r = 0; r < 4; ++r) {
                const int m = m0 + kg * 4 + r;   // D row
                z[(size_t)dir * M_TOT * HID + (size_t)m * HID + h] = acc[r] + bias;
            }
        }
    }
}

// DPP helpers — guaranteed VALU lane exchange (no LDS).
__device__ __forceinline__ float dpp_qxor1(float x) {
    int i = __float_as_int(x);
    i = __builtin_amdgcn_update_dpp(0, i, 0xB1, 0xF, 0xF, false);
    return __int_as_float(i);
}
__device__ __forceinline__ float dpp_qxor2(float x) {
    int i = __float_as_int(x);
    i = __builtin_amdgcn_update_dpp(0, i, 0x4E, 0xF, 0xF, false);
    return __int_as_float(i);
}
__device__ __forceinline__ float dpp_hmir(float x) {  // lane ^ 7
    int i = __float_as_int(x);
    i = __builtin_amdgcn_update_dpp(0, i, 0x141, 0xF, 0xF, false);
    return __int_as_float(i);
}

// ---------------- recurrent scan (R6 core; hi/lo bf16 output) ----------------
__global__ __launch_bounds__(256) void scan_kernel(
    const float* __restrict__ z,    // [2][M][HID]
    const float* __restrict__ Whh,  // [2][HID][HID] for this layer
    ushort_t* __restrict__ ohi,     // [M][KPAD] bf16 hi
    ushort_t* __restrict__ olo)     // [M][KPAD] bf16 lo
{
    const int dir = blockIdx.x >> 6;
    const int b   = blockIdx.x & 63;
    const int tid = threadIdx.x;
    const int w   = tid >> 6;
    const int lane= tid & 63;
    const int q   = lane & 3;
    const int b2  = (lane >> 2) & 1;
    const int ks  = q | (b2 << 2);
    const int slot= (lane >> 3) + 8 * w;
    const bool active = (slot < 25);
    const int slotc = active ? slot : 24;
    const int jout = 4 * slotc + q;
    const bool writer = active && (b2 == 0);
    const int kb = 12 * ks;

    __shared__ float h_lds[2][112];
    for (int i = tid; i < 224; i += 256) (&h_lds[0][0])[i] = 0.f;

    float w4[4][16];
    #pragma unroll
    for (int r = 0; r < 4; ++r) {
        const float* wr = Whh + ((size_t)dir * HID + 4 * slotc + r) * HID + kb;
        #pragma unroll
        for (int i = 0; i < 4; ++i) {
            float4 v = *(const float4*)(wr + 4 * i);
            w4[r][4*i+0] = v.x; w4[r][4*i+1] = v.y;
            w4[r][4*i+2] = v.z; w4[r][4*i+3] = v.w;
        }
        if (ks > 0) {
            w4[r][0] = 0.f; w4[r][1] = 0.f; w4[r][2] = 0.f; w4[r][3] = 0.f;
        }
    }
    __syncthreads();

    const ptrdiff_t zstride = BATCH * HID;
    const ptrdiff_t ostride = BATCH * KPAD;     // ushort units
    const int t0 = dir ? (T_LEN - 1) : 0;
    const ptrdiff_t zstep = dir ? -zstride : zstride;
    const ptrdiff_t ostep = dir ? -ostride : ostride;
    const ptrdiff_t zstep2 = 2 * zstep, zstep3 = 3 * zstep, zstep4 = 4 * zstep;

    const float* zp = z + (size_t)dir * M_TOT * HID + (size_t)b * HID + jout
                        + (ptrdiff_t)t0 * zstride;
    ushort_t* oph = ohi + ((size_t)t0 * BATCH + b) * KPAD + dir * HID + jout;
    ushort_t* opl = olo + ((size_t)t0 * BATCH + b) * KPAD + dir * HID + jout;

    float zr0 = zp[0];
    float zr1 = zp[zstep];
    float zr2 = zp[zstep2];
    float zr3 = zp[zstep3];
    const float* zpf = zp + zstep4;

#define RNN_STEP(ZREG, DO_PF, PFOFF, RD, WRB)                           \
  do {                                                                  \
    const float zin = ZREG;                                             \
    if (DO_PF) ZREG = *(zpf + (PFOFF));                                 \
    const float4* hp = (const float4*)((RD) + kb);                      \
    float a0 = 0.f, a1 = 0.f, a2 = 0.f, a3 = 0.f;                       \
    _Pragma("unroll")                                                   \
    for (int i = 0; i < 4; ++i) {                                       \
      float4 hv = hp[i];                                                \
      a0 += w4[0][4*i+0] * hv.x; a0 += w4[0][4*i+1] * hv.y;             \
      a0 += w4[0][4*i+2] * hv.z; a0 += w4[0][4*i+3] * hv.w;             \
      a1 += w4[1][4*i+0] * hv.x; a1 += w4[1][4*i+1] * hv.y;             \
      a1 += w4[1][4*i+2] * hv.z; a1 += w4[1][4*i+3] * hv.w;             \
      a2 += w4[2][4*i+0] * hv.x; a2 += w4[2][4*i+1] * hv.y;             \
      a2 += w4[2][4*i+2] * hv.z; a2 += w4[2][4*i+3] * hv.w;             \
      a3 += w4[3][4*i+0] * hv.x; a3 += w4[3][4*i+1] * hv.y;             \
      a3 += w4[3][4*i+2] * hv.z; a3 += w4[3][4*i+3] * hv.w;             \
    }                                                                   \
    float t0_ = a0 + dpp_hmir(a0);                                      \
    float t1_ = a1 + dpp_hmir(a1);                                      \
    float t2_ = a2 + dpp_hmir(a2);                                      \
    float t3_ = a3 + dpp_hmir(a3);                                      \
    float k01 = (q & 1) ? t1_ : t0_;                                    \
    float s01s = (q & 1) ? t0_ : t1_;                                   \
    float s01 = k01 + dpp_qxor1(s01s);                                  \
    float k23 = (q & 1) ? t3_ : t2_;                                    \
    float s23s = (q & 1) ? t2_ : t3_;                                   \
    float s23 = k23 + dpp_qxor1(s23s);                                  \
    float kf = (q & 2) ? s23 : s01;                                     \
    float sf = (q & 2) ? s01 : s23;                                     \
    float tot = kf + dpp_qxor2(sf);                                     \
    float xin = zin + tot;                                              \
    float ax = fabsf(xin);                                              \
    float e = __expf(2.f * ax);                                         \
    float r = 1.f - 2.f / (e + 1.f);                                    \
    float val = copysignf(r, xin);                                      \
    if (writer) {                                                       \
      (WRB)[jout] = val;                                                \
      unsigned hr = bf16_rne(val);                                      \
      float hv2 = __uint_as_float(hr << 16);                            \
      unsigned lr = bf16_rne(val - hv2);                                \
      *oph = (ushort_t)hr;                                              \
      *opl = (ushort_t)lr;                                              \
    }                                                                   \
    oph += ostep; opl += ostep;                                         \
    asm volatile("s_waitcnt lgkmcnt(0)" ::: "memory");                  \
    __builtin_amdgcn_sched_barrier(0);                                  \
    __builtin_amdgcn_s_barrier();                                       \
    __builtin_amdgcn_sched_barrier(0);                                  \
  } while (0)

    float* const h0 = &h_lds[0][0];
    float* const h1 = &h_lds[1][0];

    for (int g = 0; g < (T_LEN / 4) - 1; ++g) {
        RNN_STEP(zr0, 1, 0,      h0, h1);
        RNN_STEP(zr1, 1, zstep,  h1, h0);
        RNN_STEP(zr2, 1, zstep2, h0, h1);
        RNN_STEP(zr3, 1, zstep3, h1, h0);
        zpf += zstep4;
    }
    RNN_STEP(zr0, 0, 0, h0, h1);
    RNN_STEP(zr1, 0, 0, h1, h0);
    RNN_STEP(zr2, 0, 0, h0, h1);
    RNN_STEP(zr3, 0, 0, h1, h0);

#undef RNN_STEP
}

// ---------------- output projection (reads hi+lo) ----------------
__global__ __launch_bounds__(256) void outproj_kernel(
    const ushort_t* __restrict__ hh, const ushort_t* __restrict__ hl,
    const float* __restrict__ Wout, const float* __restrict__ bout,
    float* __restrict__ y)
{
    const int gid = blockIdx.x * 256 + threadIdx.x;
    const int wid = gid >> 6;
    const int lane = threadIdx.x & 63;
    if (wid >= M_TOT) return;
    const ushort_t* rh = hh + (size_t)wid * KPAD;
    const ushort_t* rl = hl + (size_t)wid * KPAD;
    float acc = 0.f;
    for (int k = lane; k < 200; k += 64) {
        float hv = __uint_as_float((unsigned)rh[k] << 16)
                 + __uint_as_float((unsigned)rl[k] << 16);
        acc += hv * Wout[k];
    }
    #pragma unroll
    for (int off = 32; off > 0; off >>= 1) acc += __shfl_xor(acc, off);
    if (lane == 0) y[wid] = 1.f / (1.f + __expf(-(acc + bout[0])));
}

extern "C" void kernel_launch(void* const* d_in, const int* in_sizes, int n_in,
                              void* d_out, int out_size, void* d_ws, size_t ws_size,
                              hipStream_t stream)
{
    const float* x     = (const float*)d_in[0];
    const float* W_ih0 = (const float*)d_in[1];
    const float* W_ih  = (const float*)d_in[2];
    const float* W_hh  = (const float*)d_in[3];
    const float* b_ih  = (const float*)d_in[4];
    const float* b_hh  = (const float*)d_in[5];
    const float* W_out = (const float*)d_in[6];
    const float* b_out = (const float*)d_in[7];
    float* y = (float*)d_out;

    float* z = (float*)d_ws;                                  // 2*M*100 f32
    ushort_t* hiA = (ushort_t*)(z + (size_t)2 * M_TOT * HID); // [M][KPAD]
    ushort_t* loA = hiA + (size_t)M_TOT * KPAD;
    ushort_t* hiB = loA + (size_t)M_TOT * KPAD;
    ushort_t* loB = hiB + (size_t)M_TOT * KPAD;
    ushort_t* whi = loB + (size_t)M_TOT * KPAD;               // [NPAD][KPAD]
    ushort_t* wlo = whi + (size_t)NPAD * KPAD;

    zeropad_kernel<<<(M_TOT * 24 + 255) / 256, 256, 0, stream>>>(hiA, loA, hiB, loB);

    // layer 0: fp32 GEMM (x, K=100) -> z ; scan -> A
    ingemm_kernel<<<dim3(M_TOT / 128, 4), 256, 0, stream>>>(
        x, W_ih0, b_ih, b_hh, z, 100);
    scan_kernel<<<128, 256, 0, stream>>>(z, W_hh, hiA, loA);

    for (int l = 1; l < 10; ++l) {
        const ushort_t* ih = (l & 1) ? hiA : hiB;
        const ushort_t* il = (l & 1) ? loA : loB;
        ushort_t* oh = (l & 1) ? hiB : hiA;
        ushort_t* ol = (l & 1) ? loB : loA;
        wsplit_kernel<<<(NPAD * KPAD + 255) / 256, 256, 0, stream>>>(
            W_ih + (size_t)(l - 1) * 2 * 100 * 200, whi, wlo);
        ingemm_mfma_kernel<<<512, 256, 0, stream>>>(
            ih, il, whi, wlo, b_ih + l * 200, b_hh + l * 200, z);
        scan_kernel<<<128, 256, 0, stream>>>(
            z, W_hh + (size_t)l * 2 * HID * HID, oh, ol);
    }
    // layer 9 (odd) wrote hiB/loB
    outproj_kernel<<<M_TOT / 4, 256, 0, stream>>>(hiB, loB, W_out, b_out, y);
}

// Round 10
// 2069.565 us; speedup vs baseline: 1.0890x; 1.0196x over previous
//
#include <hip/hip_runtime.h>
#include <math.h>

// Bidirectional 10-layer tanh RNN, T=512 B=64 H=100, + sigmoid head.
// R10: R9's split-bf16 MFMA ingemm kept (layers 1..9, ~17us vs 43 fp32).
// Scan regression (173.6 -> 182us) traced to the TWO scattered b16 hi/lo
// stores per step; now packs hi|lo<<16 into ONE u32 store (store path
// instruction-identical to the proven fp32 scan). MFMA kernel unpacks
// A-frags at setup (one-time, static-index u16 extracts); B planes stay
// pre-split. All 9 W-splits hoisted into one up-front kernel (off the
// layer critical path). Layer 0 (fp32 x, K=100) keeps the R7 fp32 ingemm.

#define T_LEN 512
#define BATCH 64
#define HID   100
#define M_TOT (T_LEN * BATCH)   // 32768
#define KPAD  224               // 7 chunks of 32
#define NPAD  208               // 13 tiles of 16
#define WPLANE (NPAD * KPAD)    // 46592

typedef unsigned short ushort_t;
typedef unsigned int   uint_t;
typedef __attribute__((ext_vector_type(8))) __bf16 bf16x8;
typedef __attribute__((ext_vector_type(4))) float f32x4;
typedef __attribute__((ext_vector_type(8))) unsigned int uintx8;

// ---------------- fp32 input GEMM, layer 0 only (R7 structure, proven) ----------------
__global__ __launch_bounds__(256) void ingemm_kernel(
    const float* __restrict__ In, const float* __restrict__ W,
    const float* __restrict__ bih, const float* __restrict__ bhh,
    float* __restrict__ z, int K)
{
    __shared__ float As[16][132];
    __shared__ float Bs[16][68];
    const int tid = threadIdx.x;
    const int m0 = blockIdx.x * 128;
    const int n0 = blockIdx.y * 64;
    const int tx = tid & 15, ty = tid >> 4;
    const int lm = tid >> 2;
    const int lk = (tid & 3) << 2;

    float acc[8][4];
    #pragma unroll
    for (int i = 0; i < 8; ++i)
        #pragma unroll
        for (int j = 0; j < 4; ++j) acc[i][j] = 0.f;

    for (int k0 = 0; k0 < K; k0 += 16) {
        #pragma unroll
        for (int rep = 0; rep < 2; ++rep) {
            float4 av = make_float4(0.f,0.f,0.f,0.f);
            const int row = lm + 64 * rep;
            if (k0 + lk < K)
                av = *(const float4*)(In + (size_t)(m0 + row) * K + k0 + lk);
            As[lk+0][row]=av.x; As[lk+1][row]=av.y;
            As[lk+2][row]=av.z; As[lk+3][row]=av.w;
        }
        {
            float4 bv = make_float4(0.f,0.f,0.f,0.f);
            const int nrow = n0 + lm;
            if (nrow < 200 && k0 + lk < K)
                bv = *(const float4*)(W + (size_t)nrow * K + k0 + lk);
            Bs[lk+0][lm]=bv.x; Bs[lk+1][lm]=bv.y;
            Bs[lk+2][lm]=bv.z; Bs[lk+3][lm]=bv.w;
        }
        __syncthreads();
        #pragma unroll
        for (int kk = 0; kk < 16; ++kk) {
            float4 alo = *(const float4*)&As[kk][ty << 2];
            float4 ahi = *(const float4*)&As[kk][64 + (ty << 2)];
            float4 b4  = *(const float4*)&Bs[kk][tx << 2];
            float a[8] = {alo.x, alo.y, alo.z, alo.w,
                          ahi.x, ahi.y, ahi.z, ahi.w};
            float b[4] = {b4.x, b4.y, b4.z, b4.w};
            #pragma unroll
            for (int i = 0; i < 8; ++i)
                #pragma unroll
                for (int j = 0; j < 4; ++j)
                    acc[i][j] += a[i] * b[j];
        }
        __syncthreads();
    }
    #pragma unroll
    for (int i = 0; i < 8; ++i) {
        const int m = m0 + ((i < 4) ? ((ty << 2) + i) : (64 + (ty << 2) + (i - 4)));
        #pragma unroll
        for (int j = 0; j < 4; ++j) {
            const int n = n0 + (tx << 2) + j;
            if (n < 200) {
                const int dir = (n >= 100) ? 1 : 0;
                const int h = n - dir * 100;
                z[(size_t)dir * M_TOT * HID + (size_t)m * HID + h] =
                    acc[i][j] + bih[n] + bhh[n];
            }
        }
    }
}

// ---------------- helpers: bf16 RNE split ----------------
__device__ __forceinline__ unsigned bf16_rne(float v) {
    unsigned u = __float_as_uint(v);
    return (u + 0x7FFFu + ((u >> 16) & 1u)) >> 16;
}

// zero the pad columns (k = 200..223) of the 2 packed ping-pong arrays
__global__ __launch_bounds__(256) void zeropad_kernel(uint_t* a, uint_t* b)
{
    int i = blockIdx.x * 256 + threadIdx.x;      // M*24
    if (i >= M_TOT * 24) return;
    size_t off = (size_t)(i / 24) * KPAD + 200 + (i % 24);
    a[off] = 0; b[off] = 0;
}

// split ALL 9 layers' W_ih (fp32 [200][200]) into zero-padded bf16 hi/lo
// planes: wbuf + l*2*WPLANE = hi plane, + WPLANE = lo plane.
__global__ __launch_bounds__(256) void wsplit_all_kernel(
    const float* __restrict__ W_ih, ushort_t* __restrict__ wbuf)
{
    int i = blockIdx.x * 256 + threadIdx.x;      // 9*WPLANE = 419328
    if (i >= 9 * WPLANE) return;
    int l = i / WPLANE;
    int r = i - l * WPLANE;
    int n = r / KPAD, k = r - (r / KPAD) * KPAD;
    const float* W = W_ih + (size_t)l * 2 * 100 * 200;
    float v = (n < 200 && k < 200) ? W[n * 200 + k] : 0.f;
    unsigned hr = bf16_rne(v);
    float hv = __uint_as_float(hr << 16);
    unsigned lr = bf16_rne(v - hv);
    ushort_t* whi = wbuf + (size_t)l * 2 * WPLANE;
    whi[r] = (ushort_t)hr;
    whi[WPLANE + r] = (ushort_t)lr;
}

// ---------------- MFMA input GEMM, layers 1..9 ----------------
// In = packed u32 [M][KPAD] (hi | lo<<16); W = pre-split hi/lo planes.
// One wave per 16-row m-tile; A hi/lo frags unpacked once at setup; loop 13
// n-tiles x 7 k-chunks x 3 MFMA (hh, hl, lh). Fragment layout: lane ->
// (row = lane&15, k = 8*(lane>>4)+b); D: col = lane&15, row = (lane>>4)*4+reg.
__global__ __launch_bounds__(256) void ingemm_mfma_kernel(
    const uint_t* __restrict__ in_pk,
    const ushort_t* __restrict__ w_hi,  const ushort_t* __restrict__ w_lo,
    const float* __restrict__ bih, const float* __restrict__ bhh,
    float* __restrict__ z)
{
    const int wv   = threadIdx.x >> 6;
    const int lane = threadIdx.x & 63;
    const int mt   = blockIdx.x * 4 + wv;     // m-tile 0..2047
    const int m0   = mt * 16;
    const int r16  = lane & 15;
    const int kg   = lane >> 4;
    const int kof  = kg * 8;

    // A fragments: 7 k-chunks x {hi, lo}, unpacked from packed u32
    bf16x8 ah[7], al[7];
    const uint_t* arp = in_pk + (size_t)(m0 + r16) * KPAD + kof;
    #pragma unroll
    for (int c = 0; c < 7; ++c) {
        uintx8 p = *(const uintx8*)(arp + 32 * c);
        union { bf16x8 v; ushort_t u[8]; } hh, ll;
        #pragma unroll
        for (int i = 0; i < 8; ++i) {
            hh.u[i] = (ushort_t)(p[i] & 0xFFFFu);
            ll.u[i] = (ushort_t)(p[i] >> 16);
        }
        ah[c] = hh.v; al[c] = ll.v;
    }

    for (int nt = 0; nt < 13; ++nt) {
        const int n0 = nt * 16;
        const ushort_t* brh = w_hi + (size_t)(n0 + r16) * KPAD + kof;
        const ushort_t* brl = w_lo + (size_t)(n0 + r16) * KPAD + kof;
        f32x4 acc = {0.f, 0.f, 0.f, 0.f};
        #pragma unroll
        for (int c = 0; c < 7; ++c) {
            bf16x8 bh = *(const bf16x8*)(brh + 32 * c);
            bf16x8 bl = *(const bf16x8*)(brl + 32 * c);
            acc = __builtin_amdgcn_mfma_f32_16x16x32_bf16(ah[c], bh, acc, 0, 0, 0);
            acc = __builtin_amdgcn_mfma_f32_16x16x32_bf16(ah[c], bl, acc, 0, 0, 0);
            acc = __builtin_amdgcn_mfma_f32_16x16x32_bf16(al[c], bh, acc, 0, 0, 0);
        }
        const int n = n0 + r16;
        if (n < 200) {
            const int dir = (n >= 100) ? 1 : 0;
            const int h = n - dir * 100;
            const float bias = bih[n] + bhh[n];
            #pragma unroll
            for (int r = 0; r < 4; ++r) {
                const int m = m0 + kg * 4 + r;
                z[(size_t)dir * M_TOT * HID + (size_t)m * HID + h] = acc[r] + bias;
            }
        }
    }
}

// DPP helpers — guaranteed VALU lane exchange (no LDS).
__device__ __forceinline__ float dpp_qxor1(float x) {
    int i = __float_as_int(x);
    i = __builtin_amdgcn_update_dpp(0, i, 0xB1, 0xF, 0xF, false);
    return __int_as_float(i);
}
__device__ __forceinline__ float dpp_qxor2(float x) {
    int i = __float_as_int(x);
    i = __builtin_amdgcn_update_dpp(0, i, 0x4E, 0xF, 0xF, false);
    return __int_as_float(i);
}
__device__ __forceinline__ float dpp_hmir(float x) {  // lane ^ 7
    int i = __float_as_int(x);
    i = __builtin_amdgcn_update_dpp(0, i, 0x141, 0xF, 0xF, false);
    return __int_as_float(i);
}

// ---------------- recurrent scan (R6 core; single packed u32 output store) ----------------
__global__ __launch_bounds__(256) void scan_kernel(
    const float* __restrict__ z,    // [2][M][HID]
    const float* __restrict__ Whh,  // [2][HID][HID] for this layer
    uint_t* __restrict__ opk)       // [M][KPAD] packed bf16 hi | lo<<16
{
    const int dir = blockIdx.x >> 6;
    const int b   = blockIdx.x & 63;
    const int tid = threadIdx.x;
    const int w   = tid >> 6;
    const int lane= tid & 63;
    const int q   = lane & 3;
    const int b2  = (lane >> 2) & 1;
    const int ks  = q | (b2 << 2);
    const int slot= (lane >> 3) + 8 * w;
    const bool active = (slot < 25);
    const int slotc = active ? slot : 24;
    const int jout = 4 * slotc + q;
    const bool writer = active && (b2 == 0);
    const int kb = 12 * ks;

    __shared__ float h_lds[2][112];
    for (int i = tid; i < 224; i += 256) (&h_lds[0][0])[i] = 0.f;

    float w4[4][16];
    #pragma unroll
    for (int r = 0; r < 4; ++r) {
        const float* wr = Whh + ((size_t)dir * HID + 4 * slotc + r) * HID + kb;
        #pragma unroll
        for (int i = 0; i < 4; ++i) {
            float4 v = *(const float4*)(wr + 4 * i);
            w4[r][4*i+0] = v.x; w4[r][4*i+1] = v.y;
            w4[r][4*i+2] = v.z; w4[r][4*i+3] = v.w;
        }
        if (ks > 0) {
            w4[r][0] = 0.f; w4[r][1] = 0.f; w4[r][2] = 0.f; w4[r][3] = 0.f;
        }
    }
    __syncthreads();

    const ptrdiff_t zstride = BATCH * HID;
    const ptrdiff_t ostride = BATCH * KPAD;     // uint units
    const int t0 = dir ? (T_LEN - 1) : 0;
    const ptrdiff_t zstep = dir ? -zstride : zstride;
    const ptrdiff_t ostep = dir ? -ostride : ostride;
    const ptrdiff_t zstep2 = 2 * zstep, zstep3 = 3 * zstep, zstep4 = 4 * zstep;

    const float* zp = z + (size_t)dir * M_TOT * HID + (size_t)b * HID + jout
                        + (ptrdiff_t)t0 * zstride;
    uint_t* op = opk + ((size_t)t0 * BATCH + b) * KPAD + dir * HID + jout;

    float zr0 = zp[0];
    float zr1 = zp[zstep];
    float zr2 = zp[zstep2];
    float zr3 = zp[zstep3];
    const float* zpf = zp + zstep4;

#define RNN_STEP(ZREG, DO_PF, PFOFF, RD, WRB)                           \
  do {                                                                  \
    const float zin = ZREG;                                             \
    if (DO_PF) ZREG = *(zpf + (PFOFF));                                 \
    const float4* hp = (const float4*)((RD) + kb);                      \
    float a0 = 0.f, a1 = 0.f, a2 = 0.f, a3 = 0.f;                       \
    _Pragma("unroll")                                                   \
    for (int i = 0; i < 4; ++i) {                                       \
      float4 hv = hp[i];                                                \
      a0 += w4[0][4*i+0] * hv.x; a0 += w4[0][4*i+1] * hv.y;             \
      a0 += w4[0][4*i+2] * hv.z; a0 += w4[0][4*i+3] * hv.w;             \
      a1 += w4[1][4*i+0] * hv.x; a1 += w4[1][4*i+1] * hv.y;             \
      a1 += w4[1][4*i+2] * hv.z; a1 += w4[1][4*i+3] * hv.w;             \
      a2 += w4[2][4*i+0] * hv.x; a2 += w4[2][4*i+1] * hv.y;             \
      a2 += w4[2][4*i+2] * hv.z; a2 += w4[2][4*i+3] * hv.w;             \
      a3 += w4[3][4*i+0] * hv.x; a3 += w4[3][4*i+1] * hv.y;             \
      a3 += w4[3][4*i+2] * hv.z; a3 += w4[3][4*i+3] * hv.w;             \
    }                                                                   \
    float t0_ = a0 + dpp_hmir(a0);                                      \
    float t1_ = a1 + dpp_hmir(a1);                                      \
    float t2_ = a2 + dpp_hmir(a2);                                      \
    float t3_ = a3 + dpp_hmir(a3);                                      \
    float k01 = (q & 1) ? t1_ : t0_;                                    \
    float s01s = (q & 1) ? t0_ : t1_;                                   \
    float s01 = k01 + dpp_qxor1(s01s);                                  \
    float k23 = (q & 1) ? t3_ : t2_;                                    \
    float s23s = (q & 1) ? t2_ : t3_;                                   \
    float s23 = k23 + dpp_qxor1(s23s);                                  \
    float kf = (q & 2) ? s23 : s01;                                     \
    float sf = (q & 2) ? s01 : s23;                                     \
    float tot = kf + dpp_qxor2(sf);                                     \
    float xin = zin + tot;                                              \
    float ax = fabsf(xin);                                              \
    float e = __expf(2.f * ax);                                         \
    float r = 1.f - 2.f / (e + 1.f);                                    \
    float val = copysignf(r, xin);                                      \
    if (writer) {                                                       \
      (WRB)[jout] = val;                                                \
      unsigned hr = bf16_rne(val);                                      \
      float hv2 = __uint_as_float(hr << 16);                            \
      unsigned lr = bf16_rne(val - hv2);                                \
      *op = hr | (lr << 16);                                            \
    }                                                                   \
    op += ostep;                                                        \
    asm volatile("s_waitcnt lgkmcnt(0)" ::: "memory");                  \
    __builtin_amdgcn_sched_barrier(0);                                  \
    __builtin_amdgcn_s_barrier();                                       \
    __builtin_amdgcn_sched_barrier(0);                                  \
  } while (0)

    float* const h0 = &h_lds[0][0];
    float* const h1 = &h_lds[1][0];

    for (int g = 0; g < (T_LEN / 4) - 1; ++g) {
        RNN_STEP(zr0, 1, 0,      h0, h1);
        RNN_STEP(zr1, 1, zstep,  h1, h0);
        RNN_STEP(zr2, 1, zstep2, h0, h1);
        RNN_STEP(zr3, 1, zstep3, h1, h0);
        zpf += zstep4;
    }
    RNN_STEP(zr0, 0, 0, h0, h1);
    RNN_STEP(zr1, 0, 0, h1, h0);
    RNN_STEP(zr2, 0, 0, h0, h1);
    RNN_STEP(zr3, 0, 0, h1, h0);

#undef RNN_STEP
}

// ---------------- output projection (reads packed) ----------------
__global__ __launch_bounds__(256) void outproj_kernel(
    const uint_t* __restrict__ hpk,
    const float* __restrict__ Wout, const float* __restrict__ bout,
    float* __restrict__ y)
{
    const int gid = blockIdx.x * 256 + threadIdx.x;
    const int wid = gid >> 6;
    const int lane = threadIdx.x & 63;
    if (wid >= M_TOT) return;
    const uint_t* rp = hpk + (size_t)wid * KPAD;
    float acc = 0.f;
    for (int k = lane; k < 200; k += 64) {
        uint_t p = rp[k];
        float hv = __uint_as_float(p << 16)
                 + __uint_as_float(p & 0xFFFF0000u);
        acc += hv * Wout[k];
    }
    #pragma unroll
    for (int off = 32; off > 0; off >>= 1) acc += __shfl_xor(acc, off);
    if (lane == 0) y[wid] = 1.f / (1.f + __expf(-(acc + bout[0])));
}

extern "C" void kernel_launch(void* const* d_in, const int* in_sizes, int n_in,
                              void* d_out, int out_size, void* d_ws, size_t ws_size,
                              hipStream_t stream)
{
    const float* x     = (const float*)d_in[0];
    const float* W_ih0 = (const float*)d_in[1];
    const float* W_ih  = (const float*)d_in[2];
    const float* W_hh  = (const float*)d_in[3];
    const float* b_ih  = (const float*)d_in[4];
    const float* b_hh  = (const float*)d_in[5];
    const float* W_out = (const float*)d_in[6];
    const float* b_out = (const float*)d_in[7];
    float* y = (float*)d_out;

    float* z = (float*)d_ws;                                  // 2*M*100 f32
    uint_t* pkA = (uint_t*)(z + (size_t)2 * M_TOT * HID);     // [M][KPAD] u32
    uint_t* pkB = pkA + (size_t)M_TOT * KPAD;
    ushort_t* wbuf = (ushort_t*)(pkB + (size_t)M_TOT * KPAD); // 9 x 2 planes

    zeropad_kernel<<<(M_TOT * 24 + 255) / 256, 256, 0, stream>>>(pkA, pkB);
    wsplit_all_kernel<<<(9 * WPLANE + 255) / 256, 256, 0, stream>>>(W_ih, wbuf);

    // layer 0: fp32 GEMM (x, K=100) -> z ; scan -> A
    ingemm_kernel<<<dim3(M_TOT / 128, 4), 256, 0, stream>>>(
        x, W_ih0, b_ih, b_hh, z, 100);
    scan_kernel<<<128, 256, 0, stream>>>(z, W_hh, pkA);

    for (int l = 1; l < 10; ++l) {
        const uint_t* in = (l & 1) ? pkA : pkB;
        uint_t* out      = (l & 1) ? pkB : pkA;
        const ushort_t* whi = wbuf + (size_t)(l - 1) * 2 * WPLANE;
        ingemm_mfma_kernel<<<512, 256, 0, stream>>>(
            in, whi, whi + WPLANE, b_ih + l * 200, b_hh + l * 200, z);
        scan_kernel<<<128, 256, 0, stream>>>(
            z, W_hh + (size_t)l * 2 * HID * HID, out);
    }
    // layer 9 (odd) wrote pkB
    outproj_kernel<<<M_TOT / 4, 256, 0, stream>>>(pkB, W_out, b_out, y);
}